// Round 1
// baseline (2078.407 us; speedup 1.0000x reference)
//
#include <hip/hip_runtime.h>

#define DD 300          // feature dim
#define BK 16           // K tile
#define TM 128          // rows per block
#define TN 64           // cols per block
#define ASTRIDE 132     // 128 + 4 pad: keeps 16B alignment, breaks bank conflicts

// ---- Wl (e,d) -> WlT (d,e) so GEMM B-loads are coalesced ----
__global__ void transpose_wl(const float* __restrict__ Wl, float* __restrict__ WlT) {
    int idx = blockIdx.x * 256 + threadIdx.x;
    if (idx < DD * DD) {
        int e = idx / DD, d = idx % DD;
        WlT[d * DD + e] = Wl[e * DD + d];
    }
}

// ---- projection: one wave per row, 3 dot products of length 300 ----
// ids != nullptr => row = embedding[ids[m]] (level 0 gather, h0 never materialized)
__global__ __launch_bounds__(256) void proj_kernel(
    const float* __restrict__ src, const int* __restrict__ ids,
    const float* __restrict__ Wp, const float* __restrict__ bp,
    float* __restrict__ out, int M, int Nk, int offk)
{
    int wave = (blockIdx.x * 256 + threadIdx.x) >> 6;
    int lane = threadIdx.x & 63;
    if (wave >= M) return;
    const float* row = src + (size_t)(ids ? ids[wave] : wave) * DD;
    float a0 = 0.f, a1 = 0.f, a2 = 0.f;
    for (int d = lane; d < DD; d += 64) {
        float x = row[d];
        a0 += x * Wp[d];
        a1 += x * Wp[DD + d];
        a2 += x * Wp[2 * DD + d];
    }
    #pragma unroll
    for (int off = 32; off > 0; off >>= 1) {
        a0 += __shfl_down(a0, off);
        a1 += __shfl_down(a1, off);
        a2 += __shfl_down(a2, off);
    }
    if (lane == 0) {
        int b = wave / Nk, n = wave - b * Nk;
        float* o = out + ((size_t)b * 8191 + offk + n) * 3;
        o[0] = a0 + bp[0];
        o[1] = a1 + bp[1];
        o[2] = a2 + bp[2];
    }
}

// ---- level GEMM: hout[m, e] = relu( sum_d (x[2m,d]+x[2m+1,d]) * WlT[d,e] + 2*bl[e] )
// Flattened (b,n) pairing is exactly rows 2m, 2m+1 of the previous level.
// ids != nullptr => source rows are embedding[ids[2m]], embedding[ids[2m+1]] (level 1).
__global__ __launch_bounds__(256) void level_kernel(
    const float* __restrict__ src, const int* __restrict__ ids,
    const float* __restrict__ WlT, const float* __restrict__ bl,
    float* __restrict__ hout, int M)
{
    __shared__ float As[BK][ASTRIDE];   // [k][row], padded
    __shared__ float Bs[BK][TN];        // [k][col]
    int tid = threadIdx.x;
    int tx = tid & 15, ty = tid >> 4;   // 16x16 thread grid; micro-tile 8 rows x 4 cols
    int row0 = blockIdx.x * TM;
    int col0 = blockIdx.y * TN;
    float acc[8][4] = {};

    for (int k0 = 0; k0 < DD; k0 += BK) {
        // stage A: 128 rows x 16 k. 16-lane groups read 64B runs of one source row.
        #pragma unroll
        for (int j = 0; j < 8; ++j) {
            int idx = tid + j * 256;
            int i = idx >> 4, k = idx & 15;
            int gk = k0 + k, m = row0 + i;
            float v = 0.f;
            if (gk < DD && m < M) {
                size_t r0 = ids ? (size_t)ids[2 * m]     : (size_t)(2 * m);
                size_t r1 = ids ? (size_t)ids[2 * m + 1] : (size_t)(2 * m + 1);
                v = src[r0 * DD + gk] + src[r1 * DD + gk];
            }
            As[k][i] = v;
        }
        // stage B: 16 k x 64 cols, fully coalesced from WlT.
        #pragma unroll
        for (int j = 0; j < 4; ++j) {
            int idx = tid + j * 256;
            int e = idx & 63, k = idx >> 6;
            int gk = k0 + k, ge = col0 + e;
            Bs[k][e] = (gk < DD && ge < DD) ? WlT[(size_t)gk * DD + ge] : 0.f;
        }
        __syncthreads();
        #pragma unroll
        for (int kk = 0; kk < BK; ++kk) {
            const float4* ap = (const float4*)&As[kk][ty * 8];
            float4 av0 = ap[0], av1 = ap[1];
            float4 bv = *(const float4*)&Bs[kk][tx * 4];
            float a[8] = {av0.x, av0.y, av0.z, av0.w, av1.x, av1.y, av1.z, av1.w};
            float b[4] = {bv.x, bv.y, bv.z, bv.w};
            #pragma unroll
            for (int r = 0; r < 8; ++r)
                #pragma unroll
                for (int c = 0; c < 4; ++c)
                    acc[r][c] += a[r] * b[c];
        }
        __syncthreads();
    }

    #pragma unroll
    for (int r = 0; r < 8; ++r) {
        int m = row0 + ty * 8 + r;
        if (m >= M) continue;
        #pragma unroll
        for (int c = 0; c < 4; ++c) {
            int e = col0 + tx * 4 + c;
            if (e < DD) {
                float v = acc[r][c] + 2.f * bl[e];
                hout[(size_t)m * DD + e] = v > 0.f ? v : 0.f;
            }
        }
    }
}

extern "C" void kernel_launch(void* const* d_in, const int* in_sizes, int n_in,
                              void* d_out, int out_size, void* d_ws, size_t ws_size,
                              hipStream_t stream)
{
    const int*   word_ids  = (const int*)d_in[0];    // (32, 4096) int32
    const float* embedding = (const float*)d_in[1];  // (50000, 300) f32
    const float* Wl        = (const float*)d_in[2];  // (300, 300) f32
    const float* bl        = (const float*)d_in[3];  // (300,) f32
    const float* Wp        = (const float*)d_in[4];  // (3, 300) f32
    const float* bp        = (const float*)d_in[5];  // (3,) f32
    float* out = (float*)d_out;

    // ws layout: WlT (360 KB) | hA (78.6 MB, max M=65536) | hB (39.3 MB, max M=32768)
    char* ws = (char*)d_ws;
    float* WlT = (float*)ws;
    size_t off = 360448;  // 256-aligned past 300*300*4
    float* hA = (float*)(ws + off);
    float* hB = (float*)(ws + off + (size_t)65536 * DD * sizeof(float));

    transpose_wl<<<(DD * DD + 255) / 256, 256, 0, stream>>>(Wl, WlT);

    // level 0 projection straight off the gather (h0 never materialized)
    int M0 = 32 * 4096;
    proj_kernel<<<(M0 + 3) / 4, 256, 0, stream>>>(embedding, word_ids, Wp, bp, out, M0, 4096, 0);

    const float* src = embedding;
    const int* ids = word_ids;      // level 1 gathers directly from the table
    int M = M0, Nk = 4096, offk = 0;
    float* bufs[2] = {hA, hB};
    for (int k = 1; k <= 12; ++k) {
        offk += Nk; Nk >>= 1; M >>= 1;
        float* hout = bufs[(k - 1) & 1];   // ping-pong; sizes shrink so always fits
        dim3 grid((M + TM - 1) / TM, (DD + TN - 1) / TN);
        level_kernel<<<grid, 256, 0, stream>>>(src, ids, WlT, bl, hout, M);
        proj_kernel<<<(M + 3) / 4, 256, 0, stream>>>(hout, nullptr, Wp, bp, out, M, Nk, offk);
        src = hout; ids = nullptr;
    }
}

// Round 2
// 981.269 us; speedup vs baseline: 2.1181x; 2.1181x over previous
//
#include <hip/hip_runtime.h>

#define DD 300          // feature dim
#define KP 320          // K padded to 10 x 32
#define NT 19           // n-tiles of 16 covering 304 >= 300

typedef __attribute__((ext_vector_type(8))) short short8;   // 8 bf16 = 4 VGPRs (MFMA A/B frag)
typedef __attribute__((ext_vector_type(4))) float f32x4;    // MFMA C/D frag

__device__ inline unsigned short bf16_rne(float x) {
    union { float f; unsigned u; } v; v.f = x;
    v.u += 0x7FFF + ((v.u >> 16) & 1);
    return (unsigned short)(v.u >> 16);
}
__device__ inline float bf16_to_f32(unsigned short h) {
    union { unsigned u; float f; } v; v.u = (unsigned)h << 16;
    return v.f;
}

// ---- split Wl (n,k layout == B-fragment layout, no transpose) into padded bf16 hi/lo planes ----
__global__ void split_w(const float* __restrict__ Wl, short* __restrict__ Whi, short* __restrict__ Wlo) {
    int idx = blockIdx.x * 256 + threadIdx.x;
    if (idx >= KP * KP) return;
    int n = idx / KP, k = idx % KP;
    float v = (n < DD && k < DD) ? Wl[n * DD + k] : 0.f;
    unsigned short hi = bf16_rne(v);
    Whi[idx] = (short)hi;
    Wlo[idx] = (short)bf16_rne(v - bf16_to_f32(hi));
}

// ---- projection: one wave per row, 3 dot products of length 300 ----
__global__ __launch_bounds__(256) void proj_kernel(
    const float* __restrict__ src, const int* __restrict__ ids,
    const float* __restrict__ Wp, const float* __restrict__ bp,
    float* __restrict__ out, int M, int Nk, int offk)
{
    int wave = (blockIdx.x * 256 + threadIdx.x) >> 6;
    int lane = threadIdx.x & 63;
    if (wave >= M) return;
    const float* row = src + (size_t)(ids ? ids[wave] : wave) * DD;
    float a0 = 0.f, a1 = 0.f, a2 = 0.f;
    for (int d = lane; d < DD; d += 64) {
        float x = row[d];
        a0 += x * Wp[d];
        a1 += x * Wp[DD + d];
        a2 += x * Wp[2 * DD + d];
    }
    #pragma unroll
    for (int off = 32; off > 0; off >>= 1) {
        a0 += __shfl_down(a0, off);
        a1 += __shfl_down(a1, off);
        a2 += __shfl_down(a2, off);
    }
    if (lane == 0) {
        int b = wave / Nk, n = wave - b * Nk;
        float* o = out + ((size_t)b * 8191 + offk + n) * 3;
        o[0] = a0 + bp[0];
        o[1] = a1 + bp[1];
        o[2] = a2 + bp[2];
    }
}

// ---- level GEMM via split-bf16 3-MFMA: h[m,n] = relu( sum_k (x[2m,k]+x[2m+1,k]) * Wl[n,k] + 2bl[n] )
// Wave-independent: each wave owns 32 rows (2 m-tiles) x 300 cols (19 n-tiles). No LDS, no barriers.
// A-fragments built in-register (pair-sum + hi/lo split); each source element read exactly once.
__global__ __launch_bounds__(256, 2) void level_mfma(
    const float* __restrict__ src, const int* __restrict__ ids,
    const short* __restrict__ Whi, const short* __restrict__ Wlo,
    const float* __restrict__ bl, float* __restrict__ hout, int M)
{
    int wave = blockIdx.x * 4 + (threadIdx.x >> 6);
    int lane = threadIdx.x & 63;
    int m0 = wave * 32;
    if (m0 >= M) return;
    int r = lane & 15;      // A row-in-tile / B col / C col
    int q = lane >> 4;      // k-group for A/B frags, row-group for C

    int mA = m0 + r, mB = mA + 16;
    long a0i, a1i, b0i, b1i;
    if (ids) { a0i = ids[2 * mA]; a1i = ids[2 * mA + 1]; b0i = ids[2 * mB]; b1i = ids[2 * mB + 1]; }
    else     { a0i = 2 * mA; a1i = a0i + 1; b0i = 2 * mB; b1i = b0i + 1; }
    const float* pa0 = src + a0i * DD;
    const float* pa1 = src + a1i * DD;
    const float* pb0 = src + b0i * DD;
    const float* pb1 = src + b1i * DD;

    const short* wh = Whi + (long)r * KP;
    const short* wl = Wlo + (long)r * KP;

    f32x4 acc0[NT] = {};
    f32x4 acc1[NT] = {};

    for (int k0 = 0; k0 < KP; k0 += 32) {
        int kk = k0 + q * 8;            // this lane's 8-k chunk
        float x[8], y[8];
        if (kk + 8 <= DD) {             // fast path: aligned float4 pair loads
            const f32x4* A0 = (const f32x4*)(pa0 + kk);
            const f32x4* A1 = (const f32x4*)(pa1 + kk);
            const f32x4* B0 = (const f32x4*)(pb0 + kk);
            const f32x4* B1 = (const f32x4*)(pb1 + kk);
            f32x4 s0 = A0[0] + A1[0], s1 = A0[1] + A1[1];
            f32x4 t0 = B0[0] + B1[0], t1 = B0[1] + B1[1];
            #pragma unroll
            for (int i = 0; i < 4; ++i) { x[i] = s0[i]; x[4 + i] = s1[i]; y[i] = t0[i]; y[4 + i] = t1[i]; }
        } else {                        // tail k-step: element guards, pad with 0
            #pragma unroll
            for (int i = 0; i < 8; ++i) {
                int kg = kk + i;
                bool ok = kg < DD;
                x[i] = ok ? (pa0[kg] + pa1[kg]) : 0.f;
                y[i] = ok ? (pb0[kg] + pb1[kg]) : 0.f;
            }
        }
        // split to bf16 hi/lo
        short8 xhi, xlo, yhi, ylo;
        #pragma unroll
        for (int i = 0; i < 8; ++i) {
            unsigned short h = bf16_rne(x[i]);
            xhi[i] = (short)h;
            xlo[i] = (short)bf16_rne(x[i] - bf16_to_f32(h));
            h = bf16_rne(y[i]);
            yhi[i] = (short)h;
            ylo[i] = (short)bf16_rne(y[i] - bf16_to_f32(h));
        }
        #pragma unroll
        for (int t = 0; t < NT; ++t) {
            short8 bh = *(const short8*)(wh + (long)t * 16 * KP + kk);
            short8 bo = *(const short8*)(wl + (long)t * 16 * KP + kk);
            acc0[t] = __builtin_amdgcn_mfma_f32_16x16x32_bf16(xhi, bh, acc0[t], 0, 0, 0);
            acc0[t] = __builtin_amdgcn_mfma_f32_16x16x32_bf16(xhi, bo, acc0[t], 0, 0, 0);
            acc0[t] = __builtin_amdgcn_mfma_f32_16x16x32_bf16(xlo, bh, acc0[t], 0, 0, 0);
            acc1[t] = __builtin_amdgcn_mfma_f32_16x16x32_bf16(yhi, bh, acc1[t], 0, 0, 0);
            acc1[t] = __builtin_amdgcn_mfma_f32_16x16x32_bf16(yhi, bo, acc1[t], 0, 0, 0);
            acc1[t] = __builtin_amdgcn_mfma_f32_16x16x32_bf16(ylo, bh, acc1[t], 0, 0, 0);
        }
    }

    // epilogue: C/D layout col=lane&15, row=(lane>>4)*4+reg (m89-verified)
    #pragma unroll
    for (int t = 0; t < NT; ++t) {
        int n = t * 16 + r;
        if (n < DD) {
            float b2 = 2.f * bl[n];
            #pragma unroll
            for (int g = 0; g < 4; ++g) {
                int m = m0 + q * 4 + g;
                float v0 = acc0[t][g] + b2;
                hout[(long)m * DD + n] = v0 > 0.f ? v0 : 0.f;
                float v1 = acc1[t][g] + b2;
                hout[(long)(m + 16) * DD + n] = v1 > 0.f ? v1 : 0.f;
            }
        }
    }
}

extern "C" void kernel_launch(void* const* d_in, const int* in_sizes, int n_in,
                              void* d_out, int out_size, void* d_ws, size_t ws_size,
                              hipStream_t stream)
{
    const int*   word_ids  = (const int*)d_in[0];    // (32, 4096) int32
    const float* embedding = (const float*)d_in[1];  // (50000, 300) f32
    const float* Wl        = (const float*)d_in[2];  // (300, 300) f32
    const float* bl        = (const float*)d_in[3];  // (300,) f32
    const float* Wp        = (const float*)d_in[4];  // (3, 300) f32
    const float* bp        = (const float*)d_in[5];  // (3,) f32
    float* out = (float*)d_out;

    // ws: hA (65536x300 f32 = 78.64 MB) | hB (32768x300 f32 = 39.32 MB) | Whi | Wlo (bf16 planes)
    char* ws = (char*)d_ws;
    float* hA  = (float*)ws;
    float* hB  = (float*)(ws + 78643200);
    short* Whi = (short*)(ws + 78643200 + 39321600);
    short* Wlo = Whi + KP * KP;

    split_w<<<(KP * KP + 255) / 256, 256, 0, stream>>>(Wl, Whi, Wlo);

    // level 0 projection straight off the gather (h0 never materialized)
    int M0 = 32 * 4096;
    proj_kernel<<<(M0 + 3) / 4, 256, 0, stream>>>(embedding, word_ids, Wp, bp, out, M0, 4096, 0);

    const float* src = embedding;
    const int* ids = word_ids;          // level 1 gathers directly from the table
    int M = M0, Nk = 4096, offk = 0;
    for (int k = 1; k <= 12; ++k) {
        offk += Nk; Nk >>= 1; M >>= 1;
        float* hout = (k & 1) ? hA : hB;   // ping-pong
        level_mfma<<<(M + 127) / 128, 256, 0, stream>>>(src, ids, Whi, Wlo, bl, hout, M);
        proj_kernel<<<(M + 3) / 4, 256, 0, stream>>>(hout, nullptr, Wp, bp, out, M, Nk, offk);
        src = hout; ids = nullptr;
    }
}

// Round 6
// 786.519 us; speedup vs baseline: 2.6425x; 1.2476x over previous
//
#include <hip/hip_runtime.h>

#define DD 300
#define KP 320          // padded K (10 chunks of 32)
#define NT 19           // n-tiles of 16 (covers 304)
#define NCH 10          // k-chunks
#define PLANE_SH 9728   // shorts per LDS plane: 304 rows x 32 k
#define BUF_SH 19456    // shorts: hi + lo planes (single buffer, 38912 B)

typedef __attribute__((ext_vector_type(8))) short short8;
typedef __attribute__((ext_vector_type(4))) float f32x4;

__device__ __forceinline__ unsigned short bf16_rne(float x) {
    union { float f; unsigned u; } v; v.f = x;
    v.u += 0x7FFF + ((v.u >> 16) & 1);
    return (unsigned short)(v.u >> 16);
}
__device__ __forceinline__ float bf16_to_f32(unsigned short h) {
    union { unsigned u; float f; } v; v.u = (unsigned)h << 16;
    return v.f;
}

// split Wl (n,k == B-frag layout) into padded bf16 hi/lo planes [KP][KP]
__global__ void split_w(const float* __restrict__ Wl, short* __restrict__ Whi, short* __restrict__ Wlo) {
    int idx = blockIdx.x * 256 + threadIdx.x;
    if (idx >= KP * KP) return;
    int n = idx / KP, k = idx % KP;
    float v = (n < DD && k < DD) ? Wl[n * DD + k] : 0.f;
    unsigned short hi = bf16_rne(v);
    Whi[idx] = (short)hi;
    Wlo[idx] = (short)bf16_rne(v - bf16_to_f32(hi));
}

// ---- projection: one wave per row, 3 dot products of length 300 (round-2 proven) ----
__global__ __launch_bounds__(256) void proj_kernel(
    const float* __restrict__ src, const int* __restrict__ ids,
    const float* __restrict__ Wp, const float* __restrict__ bp,
    float* __restrict__ out, int M, int Nk, int offk)
{
    int wave = (blockIdx.x * 256 + threadIdx.x) >> 6;
    int lane = threadIdx.x & 63;
    if (wave >= M) return;
    const float* row = src + (size_t)(ids ? ids[wave] : wave) * DD;
    float a0 = 0.f, a1 = 0.f, a2 = 0.f;
    for (int d = lane; d < DD; d += 64) {
        float x = row[d];
        a0 += x * Wp[d];
        a1 += x * Wp[DD + d];
        a2 += x * Wp[2 * DD + d];
    }
    #pragma unroll
    for (int off = 32; off > 0; off >>= 1) {
        a0 += __shfl_down(a0, off);
        a1 += __shfl_down(a1, off);
        a2 += __shfl_down(a2, off);
    }
    if (lane == 0) {
        int b = wave / Nk, n = wave - b * Nk;
        float* o = out + ((size_t)b * 8191 + offk + n) * 3;
        o[0] = a0 + bp[0];
        o[1] = a1 + bp[1];
        o[2] = a2 + bp[2];
    }
}

// Level GEMM (round-2 proven body): pair-sum, split-bf16 3-MFMA, ReLU, h write.
// NO fused projections (round-6 bisection). W staged per 32-k chunk through LDS
// via plain global loads + ds_write_b128, single buffer, two barriers per chunk.
__global__ __launch_bounds__(256, 2) void level_mfma(
    const float* __restrict__ src, const int* __restrict__ ids,
    const short* __restrict__ Whi, const short* __restrict__ Wlo,
    const float* __restrict__ bl, float* __restrict__ hout, int M)
{
    __shared__ __align__(16) short wbuf[BUF_SH];
    int tid = threadIdx.x;
    int wid = tid >> 6, lane = tid & 63;
    int r = lane & 15, q = lane >> 4;
    int m0 = blockIdx.x * 128 + wid * 32;
    bool active = m0 < M;       // wave-uniform; inactive waves still stage + barrier

    long a0i = 0, a1i = 0, b0i = 0, b1i = 0;
    if (active) {
        int mA = m0 + r, mB = mA + 16;
        if (ids) { a0i = ids[2 * mA]; a1i = ids[2 * mA + 1]; b0i = ids[2 * mB]; b1i = ids[2 * mB + 1]; }
        else     { a0i = 2l * mA; a1i = a0i + 1; b0i = 2l * mB; b1i = b0i + 1; }
    }
    const float* p0 = src + a0i * DD;
    const float* p1 = src + a1i * DD;
    const float* p2 = src + b0i * DD;
    const float* p3 = src + b1i * DD;

    // stage one 32-k chunk of both planes into LDS: plain loads + ds_write_b128
    auto stage = [&](int c) {
        for (int s = wid; s < 2 * NT; s += 4) {
            int pl = s >= NT ? 1 : 0;
            int ss = s - pl * NT;
            const short* gpl = pl ? Wlo : Whi;
            short8 v = *(const short8*)(gpl + (long)(ss * 16 + (lane >> 2)) * KP + c * 32 + (lane & 3) * 8);
            *(short8*)&wbuf[pl * PLANE_SH + ss * 512 + lane * 8] = v;
        }
    };
    // load this lane's 8-k pieces of the 4 source rows
    auto loadx = [&](int c, f32x4* x) {
        int kk = c * 32 + q * 8;
        if (kk + 8 <= DD) {
            x[0] = *(const f32x4*)(p0 + kk); x[1] = *(const f32x4*)(p0 + kk + 4);
            x[2] = *(const f32x4*)(p1 + kk); x[3] = *(const f32x4*)(p1 + kk + 4);
            x[4] = *(const f32x4*)(p2 + kk); x[5] = *(const f32x4*)(p2 + kk + 4);
            x[6] = *(const f32x4*)(p3 + kk); x[7] = *(const f32x4*)(p3 + kk + 4);
        } else {
            const float* ps[4] = {p0, p1, p2, p3};
            #pragma unroll
            for (int j = 0; j < 4; ++j)
                #pragma unroll
                for (int i = 0; i < 8; ++i) {
                    int kg = kk + i;
                    x[j * 2 + (i >> 2)][i & 3] = (kg < DD) ? ps[j][kg] : 0.f;
                }
        }
    };

    f32x4 acc0[NT] = {};
    f32x4 acc1[NT] = {};
    f32x4 xc[8], xn[8];

    loadx(0, xc);

    #pragma unroll 1
    for (int c = 0; c < NCH; ++c) {
        __syncthreads();                        // all waves done reading wbuf (chunk c-1)
        stage(c);
        __syncthreads();                        // chunk c fully written & visible
        if (c + 1 < NCH) loadx(c + 1, xn);

        // pair sums + split to bf16 hi/lo
        f32x4 sA0 = xc[0] + xc[2], sA1 = xc[1] + xc[3];
        f32x4 sB0 = xc[4] + xc[6], sB1 = xc[5] + xc[7];
        short8 xhi, xlo, yhi, ylo;
        #pragma unroll
        for (int i = 0; i < 4; ++i) {
            unsigned short h; float v;
            v = sA0[i]; h = bf16_rne(v); xhi[i]     = (short)h; xlo[i]     = (short)bf16_rne(v - bf16_to_f32(h));
            v = sA1[i]; h = bf16_rne(v); xhi[4 + i] = (short)h; xlo[4 + i] = (short)bf16_rne(v - bf16_to_f32(h));
            v = sB0[i]; h = bf16_rne(v); yhi[i]     = (short)h; ylo[i]     = (short)bf16_rne(v - bf16_to_f32(h));
            v = sB1[i]; h = bf16_rne(v); yhi[4 + i] = (short)h; ylo[4 + i] = (short)bf16_rne(v - bf16_to_f32(h));
        }
        const short* bhp = &wbuf[r * 32 + q * 8];
        const short* bop = bhp + PLANE_SH;
        #pragma unroll
        for (int t = 0; t < NT; ++t) {
            short8 bh = *(const short8*)(bhp + t * 512);
            short8 bo = *(const short8*)(bop + t * 512);
            acc0[t] = __builtin_amdgcn_mfma_f32_16x16x32_bf16(xhi, bh, acc0[t], 0, 0, 0);
            acc0[t] = __builtin_amdgcn_mfma_f32_16x16x32_bf16(xhi, bo, acc0[t], 0, 0, 0);
            acc0[t] = __builtin_amdgcn_mfma_f32_16x16x32_bf16(xlo, bh, acc0[t], 0, 0, 0);
            acc1[t] = __builtin_amdgcn_mfma_f32_16x16x32_bf16(yhi, bh, acc1[t], 0, 0, 0);
            acc1[t] = __builtin_amdgcn_mfma_f32_16x16x32_bf16(yhi, bo, acc1[t], 0, 0, 0);
            acc1[t] = __builtin_amdgcn_mfma_f32_16x16x32_bf16(ylo, bh, acc1[t], 0, 0, 0);
        }
        if (c + 1 < NCH) {
            #pragma unroll
            for (int i = 0; i < 8; ++i) xc[i] = xn[i];
        }
    }

    if (!active) return;

    // epilogue (round-2 proven): bias + ReLU + h write.
    // C/D layout: col = lane&15 (r), row = (lane>>4)*4 + reg (q*4+g)
    #pragma unroll
    for (int t = 0; t < NT; ++t) {
        int n = t * 16 + r;
        if (n < DD) {
            float b2 = 2.f * bl[n];
            #pragma unroll
            for (int g = 0; g < 4; ++g) {
                int m = m0 + q * 4 + g;
                float v0 = acc0[t][g] + b2;
                hout[(long)m * DD + n] = v0 > 0.f ? v0 : 0.f;
                float v1 = acc1[t][g] + b2;
                hout[(long)(m + 16) * DD + n] = v1 > 0.f ? v1 : 0.f;
            }
        }
    }
}

extern "C" void kernel_launch(void* const* d_in, const int* in_sizes, int n_in,
                              void* d_out, int out_size, void* d_ws, size_t ws_size,
                              hipStream_t stream)
{
    const int*   word_ids  = (const int*)d_in[0];    // (32, 4096) int32
    const float* embedding = (const float*)d_in[1];  // (50000, 300) f32
    const float* Wl        = (const float*)d_in[2];  // (300, 300) f32
    const float* bl        = (const float*)d_in[3];  // (300,) f32
    const float* Wp        = (const float*)d_in[4];  // (3, 300) f32
    const float* bp        = (const float*)d_in[5];  // (3,) f32
    float* out = (float*)d_out;

    // ws: hA (65536x300 f32) | hB (32768x300 f32) | Whi | Wlo
    char* ws = (char*)d_ws;
    float* hA  = (float*)ws;
    float* hB  = (float*)(ws + 78643200);
    short* Whi = (short*)(ws + 78643200 + 39321600);
    short* Wlo = Whi + KP * KP;

    split_w<<<(KP * KP + 255) / 256, 256, 0, stream>>>(Wl, Whi, Wlo);

    // level 0 projection straight off the gather (h0 never materialized)
    int M0 = 32 * 4096;
    proj_kernel<<<(M0 + 3) / 4, 256, 0, stream>>>(embedding, word_ids, Wp, bp, out, M0, 4096, 0);

    const float* src = embedding;
    const int* ids = word_ids;          // level 1 gathers directly from the table
    int M = M0, Nk = 4096, offk = 0;
    for (int k = 1; k <= 12; ++k) {
        offk += Nk; Nk >>= 1; M >>= 1;
        float* hout = (k & 1) ? hA : hB;   // ping-pong
        level_mfma<<<(M + 127) / 128, 256, 0, stream>>>(src, ids, Whi, Wlo, bl, hout, M);
        proj_kernel<<<(M + 3) / 4, 256, 0, stream>>>(hout, nullptr, Wp, bp, out, M, Nk, offk);
        src = hout; ids = nullptr;
    }
}

// Round 7
// 700.124 us; speedup vs baseline: 2.9686x; 1.1234x over previous
//
#include <hip/hip_runtime.h>

#define DD 300
#define KP 320          // padded K (10 chunks of 32)
#define NT 19           // n-tiles of 16 (covers 304)
#define NCH 10          // k-chunks
#define PLANE_SH 9728   // shorts per LDS plane: 304 rows x 32 k
#define BUF_SH 19456    // shorts: hi + lo planes (single buffer, 38912 B)

typedef __attribute__((ext_vector_type(8))) short short8;
typedef __attribute__((ext_vector_type(4))) float f32x4;

__device__ __forceinline__ unsigned short bf16_rne(float x) {
    union { float f; unsigned u; } v; v.f = x;
    v.u += 0x7FFF + ((v.u >> 16) & 1);
    return (unsigned short)(v.u >> 16);
}
__device__ __forceinline__ float bf16_to_f32(unsigned short h) {
    union { unsigned u; float f; } v; v.u = (unsigned)h << 16;
    return v.f;
}

// split Wl (n,k == B-frag layout) into padded bf16 hi/lo planes [KP][KP]
__global__ void split_w(const float* __restrict__ Wl, short* __restrict__ Whi, short* __restrict__ Wlo) {
    int idx = blockIdx.x * 256 + threadIdx.x;
    if (idx >= KP * KP) return;
    int n = idx / KP, k = idx % KP;
    float v = (n < DD && k < DD) ? Wl[n * DD + k] : 0.f;
    unsigned short hi = bf16_rne(v);
    Whi[idx] = (short)hi;
    Wlo[idx] = (short)bf16_rne(v - bf16_to_f32(hi));
}

// ---- level-0 projection (gather): one wave per row, statically unrolled 5-term
// dot so the row loads pipeline (round-2 proven structure, proven shuffle reduce).
__global__ __launch_bounds__(256) void proj0_kernel(
    const float* __restrict__ emb, const int* __restrict__ ids,
    const float* __restrict__ Wp, const float* __restrict__ bp,
    float* __restrict__ out, int M)
{
    int wave = (blockIdx.x * 256 + threadIdx.x) >> 6;
    int lane = threadIdx.x & 63;
    if (wave >= M) return;
    const float* row = emb + (size_t)ids[wave] * DD;
    // 300 = 4*64 + 44: four unconditional strided loads + one guarded tail
    float x0 = row[lane], x1 = row[lane + 64], x2 = row[lane + 128], x3 = row[lane + 192];
    float x4 = 0.f, wa = 0.f, wb = 0.f, wc = 0.f;
    if (lane < 44) {
        x4 = row[lane + 256];
        wa = Wp[lane + 256]; wb = Wp[DD + lane + 256]; wc = Wp[2 * DD + lane + 256];
    }
    float a0 = x0 * Wp[lane] + x1 * Wp[lane + 64] + x2 * Wp[lane + 128] + x3 * Wp[lane + 192] + x4 * wa;
    float a1 = x0 * Wp[DD + lane] + x1 * Wp[DD + lane + 64] + x2 * Wp[DD + lane + 128] + x3 * Wp[DD + lane + 192] + x4 * wb;
    float a2 = x0 * Wp[2 * DD + lane] + x1 * Wp[2 * DD + lane + 64] + x2 * Wp[2 * DD + lane + 128] + x3 * Wp[2 * DD + lane + 192] + x4 * wc;
    #pragma unroll
    for (int off = 32; off > 0; off >>= 1) {
        a0 += __shfl_down(a0, off);
        a1 += __shfl_down(a1, off);
        a2 += __shfl_down(a2, off);
    }
    if (lane == 0) {
        int b = wave >> 12, n = wave & 4095;
        float* o = out + ((size_t)b * 8191 + n) * 3;
        o[0] = a0 + bp[0];
        o[1] = a1 + bp[1];
        o[2] = a2 + bp[2];
    }
}

// Level GEMM (round-6 proven body) + fused level projection.
// Projection reduction via LDS scratch (wbuf reused after a barrier) + one
// reducer thread per row — no shuffle butterflies, no h0/pr0 path.
__global__ __launch_bounds__(256, 2) void level_mfma(
    const float* __restrict__ src, const int* __restrict__ ids,
    const short* __restrict__ Whi, const short* __restrict__ Wlo,
    const float* __restrict__ bl, const float* __restrict__ Wp, const float* __restrict__ bp,
    float* __restrict__ hout, float* __restrict__ out,
    int M, int lg, int offk)
{
    __shared__ __align__(16) short wbuf[BUF_SH];   // 38912 B; reused as pj scratch (24576 B)
    int tid = threadIdx.x;
    int wid = tid >> 6, lane = tid & 63;
    int r = lane & 15, q = lane >> 4;
    int m0 = blockIdx.x * 128 + wid * 32;
    bool active = m0 < M;       // wave-uniform; inactive waves still stage + barrier

    long a0i = 0, a1i = 0, b0i = 0, b1i = 0;
    if (active) {
        int mA = m0 + r, mB = mA + 16;
        if (ids) { a0i = ids[2 * mA]; a1i = ids[2 * mA + 1]; b0i = ids[2 * mB]; b1i = ids[2 * mB + 1]; }
        else     { a0i = 2l * mA; a1i = a0i + 1; b0i = 2l * mB; b1i = b0i + 1; }
    }
    const float* p0 = src + a0i * DD;
    const float* p1 = src + a1i * DD;
    const float* p2 = src + b0i * DD;
    const float* p3 = src + b1i * DD;

    // stage one 32-k chunk of both planes into LDS: plain loads + ds_write_b128
    auto stage = [&](int c) {
        for (int s = wid; s < 2 * NT; s += 4) {
            int pl = s >= NT ? 1 : 0;
            int ss = s - pl * NT;
            const short* gpl = pl ? Wlo : Whi;
            short8 v = *(const short8*)(gpl + (long)(ss * 16 + (lane >> 2)) * KP + c * 32 + (lane & 3) * 8);
            *(short8*)&wbuf[pl * PLANE_SH + ss * 512 + lane * 8] = v;
        }
    };
    // load this lane's 8-k pieces of the 4 source rows
    auto loadx = [&](int c, f32x4* x) {
        int kk = c * 32 + q * 8;
        if (kk + 8 <= DD) {
            x[0] = *(const f32x4*)(p0 + kk); x[1] = *(const f32x4*)(p0 + kk + 4);
            x[2] = *(const f32x4*)(p1 + kk); x[3] = *(const f32x4*)(p1 + kk + 4);
            x[4] = *(const f32x4*)(p2 + kk); x[5] = *(const f32x4*)(p2 + kk + 4);
            x[6] = *(const f32x4*)(p3 + kk); x[7] = *(const f32x4*)(p3 + kk + 4);
        } else {
            const float* ps[4] = {p0, p1, p2, p3};
            #pragma unroll
            for (int j = 0; j < 4; ++j)
                #pragma unroll
                for (int i = 0; i < 8; ++i) {
                    int kg = kk + i;
                    x[j * 2 + (i >> 2)][i & 3] = (kg < DD) ? ps[j][kg] : 0.f;
                }
        }
    };

    f32x4 acc0[NT] = {};
    f32x4 acc1[NT] = {};
    f32x4 xc[8], xn[8];

    loadx(0, xc);

    #pragma unroll 1
    for (int c = 0; c < NCH; ++c) {
        __syncthreads();                        // all waves done reading wbuf (chunk c-1)
        stage(c);
        __syncthreads();                        // chunk c fully written & visible
        if (c + 1 < NCH) loadx(c + 1, xn);

        // pair sums + split to bf16 hi/lo
        f32x4 sA0 = xc[0] + xc[2], sA1 = xc[1] + xc[3];
        f32x4 sB0 = xc[4] + xc[6], sB1 = xc[5] + xc[7];
        short8 xhi, xlo, yhi, ylo;
        #pragma unroll
        for (int i = 0; i < 4; ++i) {
            unsigned short h; float v;
            v = sA0[i]; h = bf16_rne(v); xhi[i]     = (short)h; xlo[i]     = (short)bf16_rne(v - bf16_to_f32(h));
            v = sA1[i]; h = bf16_rne(v); xhi[4 + i] = (short)h; xlo[4 + i] = (short)bf16_rne(v - bf16_to_f32(h));
            v = sB0[i]; h = bf16_rne(v); yhi[i]     = (short)h; ylo[i]     = (short)bf16_rne(v - bf16_to_f32(h));
            v = sB1[i]; h = bf16_rne(v); yhi[4 + i] = (short)h; ylo[4 + i] = (short)bf16_rne(v - bf16_to_f32(h));
        }
        const short* bhp = &wbuf[r * 32 + q * 8];
        const short* bop = bhp + PLANE_SH;
        #pragma unroll
        for (int t = 0; t < NT; ++t) {
            short8 bh = *(const short8*)(bhp + t * 512);
            short8 bo = *(const short8*)(bop + t * 512);
            acc0[t] = __builtin_amdgcn_mfma_f32_16x16x32_bf16(xhi, bh, acc0[t], 0, 0, 0);
            acc0[t] = __builtin_amdgcn_mfma_f32_16x16x32_bf16(xhi, bo, acc0[t], 0, 0, 0);
            acc0[t] = __builtin_amdgcn_mfma_f32_16x16x32_bf16(xlo, bh, acc0[t], 0, 0, 0);
            acc1[t] = __builtin_amdgcn_mfma_f32_16x16x32_bf16(yhi, bh, acc1[t], 0, 0, 0);
            acc1[t] = __builtin_amdgcn_mfma_f32_16x16x32_bf16(yhi, bo, acc1[t], 0, 0, 0);
            acc1[t] = __builtin_amdgcn_mfma_f32_16x16x32_bf16(ylo, bh, acc1[t], 0, 0, 0);
        }
        if (c + 1 < NCH) {
            #pragma unroll
            for (int i = 0; i < 8; ++i) xc[i] = xn[i];
        }
    }

    // ---- epilogue part 1 (active waves): bias + ReLU + h write + per-lane pj partials
    float pj[2][4][3] = {};
    if (active) {
        #pragma unroll
        for (int t = 0; t < NT; ++t) {
            int n = t * 16 + r;
            bool nok = n < DD;
            float w0 = nok ? Wp[n] : 0.f;
            float w1 = nok ? Wp[DD + n] : 0.f;
            float w2 = nok ? Wp[2 * DD + n] : 0.f;
            float b2 = nok ? 2.f * bl[n] : 0.f;
            #pragma unroll
            for (int g = 0; g < 4; ++g) {
                float v0 = acc0[t][g] + b2; v0 = v0 > 0.f ? v0 : 0.f;
                float v1 = acc1[t][g] + b2; v1 = v1 > 0.f ? v1 : 0.f;
                if (nok) {
                    hout[(long)(m0 + q * 4 + g) * DD + n] = v0;
                    hout[(long)(m0 + 16 + q * 4 + g) * DD + n] = v1;
                }
                pj[0][g][0] += v0 * w0; pj[0][g][1] += v0 * w1; pj[0][g][2] += v0 * w2;
                pj[1][g][0] += v1 * w0; pj[1][g][1] += v1 * w1; pj[1][g][2] += v1 * w2;
            }
        }
    }

    // ---- epilogue part 2: LDS reduction over the 16 r-lanes
    __syncthreads();                        // everyone done with wbuf K-data
    float* pjb = (float*)wbuf;              // [w][h][q][g][r][cc] = 4*2*4*4*16*3 = 6144 f32
    if (active) {
        #pragma unroll
        for (int h = 0; h < 2; ++h)
            #pragma unroll
            for (int g = 0; g < 4; ++g)
                #pragma unroll
                for (int cc = 0; cc < 3; ++cc)
                    pjb[(((((wid * 2 + h) * 4 + q) * 4 + g) * 16) + r) * 3 + cc] = pj[h][g][cc];
    }
    __syncthreads();
    if (tid < 128) {
        int m = blockIdx.x * 128 + tid;
        if (m < M) {
            int w = tid >> 5, h = (tid >> 4) & 1, qq = (tid >> 2) & 3, g = tid & 3;
            const float* base = &pjb[((((w * 2 + h) * 4 + qq) * 4 + g) * 16) * 3];
            float s0 = 0.f, s1 = 0.f, s2 = 0.f;
            #pragma unroll
            for (int rr = 0; rr < 16; ++rr) {
                s0 += base[rr * 3];
                s1 += base[rr * 3 + 1];
                s2 += base[rr * 3 + 2];
            }
            int b = m >> lg, n2 = m & ((1 << lg) - 1);
            float* o = out + ((size_t)b * 8191 + offk + n2) * 3;
            o[0] = s0 + bp[0];
            o[1] = s1 + bp[1];
            o[2] = s2 + bp[2];
        }
    }
}

extern "C" void kernel_launch(void* const* d_in, const int* in_sizes, int n_in,
                              void* d_out, int out_size, void* d_ws, size_t ws_size,
                              hipStream_t stream)
{
    const int*   word_ids  = (const int*)d_in[0];    // (32, 4096) int32
    const float* embedding = (const float*)d_in[1];  // (50000, 300) f32
    const float* Wl        = (const float*)d_in[2];  // (300, 300) f32
    const float* bl        = (const float*)d_in[3];  // (300,) f32
    const float* Wp        = (const float*)d_in[4];  // (3, 300) f32
    const float* bp        = (const float*)d_in[5];  // (3,) f32
    float* out = (float*)d_out;

    // ws: hA (65536x300 f32) | hB (32768x300 f32) | Whi | Wlo
    char* ws = (char*)d_ws;
    float* hA  = (float*)ws;
    float* hB  = (float*)(ws + 78643200);
    short* Whi = (short*)(ws + 78643200 + 39321600);
    short* Wlo = Whi + KP * KP;

    split_w<<<(KP * KP + 255) / 256, 256, 0, stream>>>(Wl, Whi, Wlo);

    // level 0 projection straight off the gather (h0 never materialized)
    int M0 = 32 * 4096;
    proj0_kernel<<<(M0 + 3) / 4, 256, 0, stream>>>(embedding, word_ids, Wp, bp, out, M0);

    const float* src = embedding;
    const int* ids = word_ids;          // level 1 gathers directly from the table
    int M = M0, Nk = 4096, offk = 0;
    for (int k = 1; k <= 12; ++k) {
        offk += Nk; Nk >>= 1; M >>= 1;
        float* hout = (k & 1) ? hA : hB;   // ping-pong
        int lg = 12 - k;
        level_mfma<<<(M + 127) / 128, 256, 0, stream>>>(src, ids, Whi, Wlo, bl, Wp, bp, hout, out, M, lg, offk);
        src = hout; ids = nullptr;
    }
}